// Round 2
// baseline (687.436 us; speedup 1.0000x reference)
//
#include <hip/hip_runtime.h>
#include <math.h>

#define NLEV 5
#define TOPKK 1000
#define NCLS 16
#define NPART 16
#define PART_CAP 256
#define CAND_TOT 2048
#define NCHUNK 3069u            // 785664 / 256
#define HISTSZ (NLEV * 256)

// level boundaries; sizes: 589824, 147456, 36864, 9216, 2304
// ALL boundaries are multiples of 256 -> a 256-thread chunk never straddles
__device__ __forceinline__ int find_level(unsigned i, unsigned& loc) {
    if (i < 589824u) { loc = i;            return 0; }
    if (i < 737280u) { loc = i - 589824u;  return 1; }
    if (i < 774144u) { loc = i - 737280u;  return 2; }
    if (i < 783360u) { loc = i - 774144u;  return 3; }
    loc = i - 783360u; return 4;
}

struct Ptrs {
    const float* anc[NLEV];
    const float* cls[NLEV];
    const float* reg[NLEV];
};

// order-preserving float32 -> uint32 (larger uint == larger float)
__device__ __forceinline__ unsigned f2key(float f) {
    unsigned u = __float_as_uint(f);
    return (u & 0x80000000u) ? ~u : (u | 0x80000000u);
}

__device__ __forceinline__ float max4(float4 v) {
    return fmaxf(fmaxf(v.x, v.y), fmaxf(v.z, v.w));
}

// ---- software grid barrier ----------------------------------------------
// bar layout (u32 idx): [g*16] 8 sub-counters (cachelines apart),
// [144] master, [160] generation. Sub/master zeroed by host memset; the
// barrier itself is GENERATION-RELATIVE (waiters compare to the gen they
// loaded), so stale gen from rocprof replays cannot deadlock it.
// Works for any nb >= 8 (group g target = #blocks with idx%8==g).
__device__ __forceinline__ void gridbar(unsigned* bar, unsigned nb) {
    __syncthreads();
    if (threadIdx.x == 0) {
        __threadfence();                                   // release our writes
        unsigned* gen = bar + 160;
        unsigned g = __hip_atomic_load(gen, __ATOMIC_ACQUIRE, __HIP_MEMORY_SCOPE_AGENT);
        unsigned grp = blockIdx.x & 7u;
        unsigned gsz = (nb + 7u - grp) / 8u;               // exact group size
        unsigned a = __hip_atomic_fetch_add(bar + grp * 16u, 1u,
                        __ATOMIC_ACQ_REL, __HIP_MEMORY_SCOPE_AGENT);
        if (a == gsz - 1u) {                               // last of my group
            __hip_atomic_store(bar + grp * 16u, 0u,
                               __ATOMIC_RELAXED, __HIP_MEMORY_SCOPE_AGENT);
            unsigned m = __hip_atomic_fetch_add(bar + 144u, 1u,
                            __ATOMIC_ACQ_REL, __HIP_MEMORY_SCOPE_AGENT);
            if (m == 7u) {                                 // last group overall
                __hip_atomic_store(bar + 144u, 0u,
                                   __ATOMIC_RELAXED, __HIP_MEMORY_SCOPE_AGENT);
                __hip_atomic_fetch_add(gen, 1u,
                                       __ATOMIC_ACQ_REL, __HIP_MEMORY_SCOPE_AGENT);
            }
        }
        while (__hip_atomic_load(gen, __ATOMIC_ACQUIRE, __HIP_MEMORY_SCOPE_AGENT) == g)
            __builtin_amdgcn_s_sleep(2);
        __threadfence();                                   // acquire others' writes
    }
    __syncthreads();
}

// suffix-scan over 256 bins, find bin holding the rem-th largest.
// aux[0] <- bin index ; aux[1] <- remainder within that bin. blockDim==256.
__device__ void suffix_select(unsigned c, unsigned rem, unsigned* s, unsigned* aux) {
    int t = threadIdx.x, r = 255 - t;          // scan over r == suffix over bin
    s[r] = c;
    __syncthreads();
    for (int d = 1; d < 256; d <<= 1) {
        unsigned v = (r >= d) ? s[r - d] : 0u;
        __syncthreads();
        s[r] += v;
        __syncthreads();
    }
    unsigned incl = s[r], above = incl - c;
    if (above < rem && rem <= incl) {          // exactly one winner thread
        aux[0] = (unsigned)t;
        aux[1] = rem - above;
    }
    __syncthreads();
}

// One persistent kernel: the radix selection is done ONCE by 5 blocks
// instead of redundantly by 3069 blocks, and 5 dispatches collapse to 1.
// Grid-stride over chunks -> correct for ANY grid size >= 64.
__global__ __launch_bounds__(256, 4) void k_fused(Ptrs p, unsigned* keys,
        unsigned* histA, unsigned* histB, unsigned* cnt, unsigned* bar,
        unsigned* selg, unsigned* thresh_g, unsigned long long* cand,
        float* out, unsigned nb) {
    __shared__ union ShU {
        unsigned long long lbuf[CAND_TOT];   // 16 KB (rank phase)
        unsigned s[256];                     // scan / per-chunk histogram
    } sh;
    __shared__ unsigned aux[33];
    __shared__ unsigned lsh[NLEV];

    const unsigned b = blockIdx.x;
    const int t = threadIdx.x;

    // ---- Phase A: keys -> global, per-chunk LDS byte-1 hist, flush ----
    for (unsigned c = b; c < NCHUNK; c += nb) {
        unsigned loc; int l = find_level(c * 256u + (unsigned)t, loc);
        const float4* cp = (const float4*)(p.cls[l]) + (size_t)loc * 4;
        float4 v0 = cp[0], v1 = cp[1], v2 = cp[2], v3 = cp[3];
        float m = fmaxf(fmaxf(max4(v0), max4(v1)), fmaxf(max4(v2), max4(v3)));
        unsigned k = f2key(m);
        keys[c * 256u + (unsigned)t] = k;
        sh.s[t] = 0u;
        __syncthreads();
        atomicAdd(&sh.s[k >> 24], 1u);
        __syncthreads();
        unsigned part = c & (NPART - 1u);
        if (sh.s[t])
            atomicAdd(&histA[part * HISTSZ + (unsigned)l * 256u + (unsigned)t], sh.s[t]);
        __syncthreads();
    }
    gridbar(bar, nb);

    // ---- Phase B: select byte-1 (blocks 0..4, once per level) ----
    if (b < NLEV) {
        unsigned c = 0;
        #pragma unroll
        for (int pp = 0; pp < NPART; pp++) c += histA[pp * HISTSZ + b * 256u + (unsigned)t];
        suffix_select(c, TOPKK, sh.s, aux);
        if (t == 0) { selg[2u * b] = aux[0]; selg[2u * b + 1u] = aux[1]; }
    }
    gridbar(bar, nb);

    // ---- Phase C: byte-2 hist of keys matching the byte-1 prefix ----
    if (t < NLEV) lsh[t] = selg[2u * (unsigned)t];
    __syncthreads();
    for (unsigned c = b; c < NCHUNK; c += nb) {
        unsigned loc; int l = find_level(c * 256u + (unsigned)t, loc);
        unsigned k = keys[c * 256u + (unsigned)t];
        sh.s[t] = 0u;
        __syncthreads();
        if ((k >> 24) == lsh[l]) atomicAdd(&sh.s[(k >> 16) & 0xFFu], 1u);
        __syncthreads();
        unsigned part = c & (NPART - 1u);
        if (sh.s[t])
            atomicAdd(&histB[part * HISTSZ + (unsigned)l * 256u + (unsigned)t], sh.s[t]);
        __syncthreads();
    }
    gridbar(bar, nb);

    // ---- Phase D: select byte-2 -> 16-bit threshold per level ----
    if (b < NLEV) {
        unsigned pf = selg[2u * b], rem1 = selg[2u * b + 1u];
        unsigned c = 0;
        #pragma unroll
        for (int pp = 0; pp < NPART; pp++) c += histB[pp * HISTSZ + b * 256u + (unsigned)t];
        suffix_select(c, rem1, sh.s, aux);
        if (t == 0) thresh_g[b] = (pf << 24) | (aux[0] << 16);
    }
    gridbar(bar, nb);

    // ---- Phase E: compact candidates ----
    if (t < NLEV) lsh[t] = thresh_g[t];
    __syncthreads();
    for (unsigned c = b; c < NCHUNK; c += nb) {
        unsigned loc; int l = find_level(c * 256u + (unsigned)t, loc);
        unsigned k = keys[c * 256u + (unsigned)t];
        if (k >= lsh[l]) {
            unsigned part = c & (NPART - 1u);
            unsigned slot = atomicAdd(&cnt[l * NPART + part], 1u);
            if (slot < PART_CAP)
                cand[((size_t)(l * NPART + part)) * PART_CAP + slot] =
                    ((unsigned long long)k << 32) | (unsigned)(~loc);
        }
    }
    gridbar(bar, nb);

    // ---- Phase F: rank-by-counting + emit (blocks 0..39, 8 per level) ----
    if (b >= (unsigned)(NLEV * 8)) return;
    const float MAXD = 4.135166556742356f;   // log(1000/16)
    int l = (int)(b >> 3);
    unsigned sl = b & 7u;

    if (t < NPART) {
        unsigned cc = cnt[l * NPART + t];
        aux[t] = (cc > PART_CAP) ? PART_CAP : cc;
    }
    __syncthreads();
    if (t == 0) {
        unsigned o = 0;
        for (int pp = 0; pp < NPART; pp++) { aux[16 + pp] = o; o += aux[pp]; }
        aux[32] = (o > CAND_TOT) ? CAND_TOT : o;
    }
    __syncthreads();
    unsigned n = aux[32];
    for (int pp = 0; pp < NPART; pp++) {
        unsigned cc = aux[pp], o = aux[16 + pp];
        for (unsigned e = (unsigned)t; e < cc; e += 256u) {
            unsigned dst = o + e;
            if (dst < CAND_TOT)
                sh.lbuf[dst] = cand[((size_t)(l * NPART + pp)) * PART_CAP + e];
        }
    }
    __syncthreads();

    unsigned j = sl * 256u + (unsigned)t;
    if (j >= n) return;
    unsigned long long my = sh.lbuf[j];
    unsigned rank = 0;
    #pragma unroll 8
    for (unsigned q = 0; q < n; q++) rank += (sh.lbuf[q] > my) ? 1u : 0u;
    if (rank >= TOPKK) return;

    unsigned idx = ~((unsigned)(my & 0xFFFFFFFFull));
    float4 an = ((const float4*)p.anc[l])[idx];
    float4 dd = ((const float4*)p.reg[l])[(size_t)idx * 2];
    float w = an.z - an.x, h = an.w - an.y;
    float cx = an.x + 0.5f * w, cy = an.y + 0.5f * h;
    float pcx = cx + dd.x * w, pcy = cy + dd.y * h;
    float pw = w * expf(fminf(dd.z, MAXD));
    float ph = h * expf(fminf(dd.w, MAXD));
    float bx = pcx - 0.5f * pw, by = pcy - 0.5f * ph;
    float bz = pcx + 0.5f * pw, bw = pcy + 0.5f * ph;

    const float4* cp = (const float4*)(p.cls[l]) + (size_t)idx * 4;
    float sg[16];
    #pragma unroll
    for (int g = 0; g < 4; g++) {
        float4 v = cp[g];
        sg[4 * g + 0] = 1.0f / (1.0f + expf(-v.x));
        sg[4 * g + 1] = 1.0f / (1.0f + expf(-v.y));
        sg[4 * g + 2] = 1.0f / (1.0f + expf(-v.z));
        sg[4 * g + 3] = 1.0f / (1.0f + expf(-v.w));
    }
    // 16 rows of [bx,by,bz,bw,score,tag] == 24 float4s, 384B contiguous
    float4* q = (float4*)(out + (size_t)(l * TOPKK + rank) * (NCLS * 6));
    #pragma unroll
    for (int g = 0; g < 8; g++) {
        float ta = (float)(2 * g + 1), tb = (float)(2 * g + 2);
        q[3 * g + 0] = make_float4(bx, by, bz, bw);
        q[3 * g + 1] = make_float4(sg[2 * g], ta, bx, by);
        q[3 * g + 2] = make_float4(bz, bw, sg[2 * g + 1], tb);
    }
}

extern "C" void kernel_launch(void* const* d_in, const int* in_sizes, int n_in,
                              void* d_out, int out_size, void* d_ws, size_t ws_size,
                              hipStream_t stream) {
    (void)in_sizes; (void)n_in; (void)out_size; (void)ws_size;
    Ptrs p;
    for (int l = 0; l < NLEV; l++) {
        p.anc[l] = (const float*)d_in[3 * l + 0];
        p.cls[l] = (const float*)d_in[3 * l + 1];
        p.reg[l] = (const float*)d_in[3 * l + 2];
    }

    // Grid size = runtime-guaranteed co-resident block count (cached).
    // Host-side queries only (no allocs/syncs) -> graph-capture safe.
    static unsigned s_nb = 0;
    if (s_nb == 0) {
        int bpcu = 0;
        if (hipOccupancyMaxActiveBlocksPerMultiprocessor(
                &bpcu, (const void*)k_fused, 256, 0) != hipSuccess || bpcu < 1)
            bpcu = 1;
        int dev = 0, ncu = 0;
        (void)hipGetDevice(&dev);
        if (hipDeviceGetAttribute(&ncu, hipDeviceAttributeMultiprocessorCount,
                                  dev) != hipSuccess || ncu < 1)
            ncu = 256;
        unsigned long long nb = (unsigned long long)bpcu * (unsigned long long)ncu;
        if (nb > 1024ull) nb = 1024ull;       // no benefit beyond 1 chunk-triple/block
        if (nb < 64ull) nb = 64ull;           // >= 40 needed for phase F; 64 always resident
        s_nb = (unsigned)nb;
    }

    char* w = (char*)d_ws;
    // layout (bytes):
    //   histA  : 0       .. 81920   \
    //   histB  : 81920   .. 163840   } one contiguous memset (165184 B)
    //   cnt    : 163840  .. 164160   }
    //   bar    : 164160  .. 165184  /   (barrier counters; gen is replay-safe)
    //   selg   : 165184  .. 165248      (written before read, no memset)
    //   thresh : 165248  .. 165312      (written before read, no memset)
    //   keys   : 165312  .. 3307968     (written before read, no memset)
    //   cand   : 3307968 .. 3471808     (guarded by cnt, no memset)
    unsigned* histA = (unsigned*)w;
    unsigned* histB = (unsigned*)(w + 81920);
    unsigned* cnt   = (unsigned*)(w + 163840);
    unsigned* bar   = (unsigned*)(w + 164160);
    unsigned* selg  = (unsigned*)(w + 165184);
    unsigned* thr   = (unsigned*)(w + 165248);
    unsigned* keys  = (unsigned*)(w + 165312);
    unsigned long long* cand = (unsigned long long*)(w + 3307968);
    float* out = (float*)d_out;

    (void)hipMemsetAsync(w, 0, 165184, stream);
    k_fused<<<dim3(s_nb), dim3(256), 0, stream>>>(p, keys, histA, histB, cnt,
                                                  bar, selg, thr, cand, out, s_nb);
}

// Round 3
// 225.309 us; speedup vs baseline: 3.0511x; 3.0511x over previous
//
#include <hip/hip_runtime.h>
#include <math.h>

#define NLEV 5
#define TOPKK 1000
#define NCLS 16
#define NPART 16                 // compact partitions (by chunk id)
#define HPART 4                  // hist16 partitions (by wave id)
#define PART_CAP 256
#define CAND_TOT 2048
#define NTOT 785664u
#define HIST16_LEV 65536u
#define HIST16_PART (NLEV * HIST16_LEV)    // 327680 u32 per partition

// level boundaries; sizes: 589824, 147456, 36864, 9216, 2304
// ALL boundaries are multiples of 256 -> a 256-thread block never straddles
__device__ __forceinline__ int find_level(unsigned i, unsigned& loc) {
    if (i < 589824u) { loc = i;            return 0; }
    if (i < 737280u) { loc = i - 589824u;  return 1; }
    if (i < 774144u) { loc = i - 737280u;  return 2; }
    if (i < 783360u) { loc = i - 774144u;  return 3; }
    loc = i - 783360u; return 4;
}

struct Ptrs {
    const float* anc[NLEV];
    const float* cls[NLEV];
    const float* reg[NLEV];
};

// order-preserving float32 -> uint32 (larger uint == larger float)
__device__ __forceinline__ unsigned f2key(float f) {
    unsigned u = __float_as_uint(f);
    return (u & 0x80000000u) ? ~u : (u | 0x80000000u);
}

__device__ __forceinline__ float max4(float4 v) {
    return fmaxf(fmaxf(v.x, v.y), fmaxf(v.z, v.w));
}

// suffix-scan over 256 bins (bin == threadIdx), find bin holding the rem-th
// largest. aux[0] <- bin ; aux[1] <- remainder within bin. blockDim==256.
// (verbatim the round-0 select core, which is absmax-0 verified)
__device__ void suffix_select(unsigned c, unsigned rem, unsigned* s, unsigned* aux) {
    int t = threadIdx.x, r = 255 - t;      // scan over r == suffix over bin
    s[r] = c;
    __syncthreads();
    for (int d = 1; d < 256; d <<= 1) {
        unsigned v = (r >= d) ? s[r - d] : 0u;
        __syncthreads();
        s[r] += v;
        __syncthreads();
    }
    unsigned incl = s[r], above = incl - c;
    if (above < rem && rem <= incl) {      // exactly one winner thread
        aux[0] = (unsigned)t;
        aux[1] = rem - above;
    }
    __syncthreads();
}

// Pass 1: key = sortable(max over 16 logits); 16-bit histogram in ONE pass.
// Bin address is byte-swapped ("swizzled") so the ~300 hot ADJACENT bins land
// on different cachelines/channels; HPART copies (by wave id) divide the
// per-line atomic convoy further. swz(bin) = (lo<<8)|hi.
__global__ __launch_bounds__(256) void k_keys_hist16(Ptrs p, unsigned* keys,
                                                     unsigned* hist16) {
    unsigned i = blockIdx.x * 256u + threadIdx.x;      // NTOT == 3069*256
    unsigned loc; int l = find_level(i, loc);
    const float4* c = (const float4*)(p.cls[l]) + (size_t)loc * 4;
    float4 a = c[0], b = c[1], d = c[2], e = c[3];
    float m = fmaxf(fmaxf(max4(a), max4(b)), fmaxf(max4(d), max4(e)));
    unsigned k = f2key(m);
    keys[i] = k;
    unsigned bin = k >> 16;
    unsigned swz = ((bin & 0xFFu) << 8) | (bin >> 8);
    unsigned part = threadIdx.x >> 6;                  // wave id 0..3
    atomicAdd(&hist16[part * HIST16_PART + (unsigned)l * HIST16_LEV + swz], 1u);
}

// Pass 2 (tiny: 1 block per level): resolve BOTH radix levels from hist16.
// Coarse bin C = high byte: thread t owns bins t*256+j, whose swizzled
// addresses are j*256+t -> column t, coalesced across the wave for fixed j.
// Fine bin F = low byte within C: swizzled address t*256+C.
// thresh = (C<<24)|(F<<16) -- identical semantics to the verified round-0
// two-round byte select.
__global__ __launch_bounds__(256) void k_select(const unsigned* hist16,
                                                unsigned* thresh_g) {
    __shared__ unsigned s[256];
    __shared__ unsigned aux[2];
    int l = blockIdx.x, t = threadIdx.x;
    const unsigned base = (unsigned)l * HIST16_LEV;

    unsigned tot = 0;
    #pragma unroll 8
    for (int j = 0; j < 256; j++) {
        unsigned idx = (unsigned)(j * 256 + t);
        #pragma unroll
        for (int pp = 0; pp < HPART; pp++)
            tot += hist16[pp * HIST16_PART + base + idx];
    }
    suffix_select(tot, TOPKK, s, aux);
    unsigned C = aux[0], rem = aux[1];
    __syncthreads();

    unsigned fc = 0;
    {
        unsigned idx = (unsigned)t * 256u + C;
        #pragma unroll
        for (int pp = 0; pp < HPART; pp++)
            fc += hist16[pp * HIST16_PART + base + idx];
    }
    suffix_select(fc, rem, s, aux);
    if (t == 0) thresh_g[l] = (C << 24) | (aux[0] << 16);
}

// Pass 3: compact keys >= level threshold (threshold now precomputed -> no
// redundant per-block selects, unlike round-0)
__global__ __launch_bounds__(256) void k_compact(const unsigned* keys,
                                                 const unsigned* thresh_g,
                                                 unsigned* cnt,
                                                 unsigned long long* cand) {
    unsigned i0 = blockIdx.x * 256u;
    unsigned loc0; int l = find_level(i0, loc0);
    unsigned thresh = thresh_g[l];                    // uniform scalar load
    unsigned k = keys[i0 + threadIdx.x];
    if (k >= thresh) {
        unsigned loc = loc0 + threadIdx.x;
        unsigned part = blockIdx.x & (NPART - 1);
        unsigned slot = atomicAdd(&cnt[l * NPART + part], 1u);
        if (slot < PART_CAP)
            cand[((size_t)(l * NPART + part)) * PART_CAP + slot] =
                ((unsigned long long)k << 32) | (unsigned)(~loc);
    }
}

// Pass 4: 8 blocks/level: stage candidates in LDS, rank-by-counting
// (composite desc == key desc, index asc == lax.top_k tie rule), winners
// decode box + write their 16 output rows. (verbatim round-0, absmax-0)
__global__ __launch_bounds__(256) void k_rank_emit(Ptrs p, const unsigned* cnt,
                                                   const unsigned long long* cand,
                                                   float* out) {
    const float MAXD = 4.135166556742356f;   // log(1000/16)
    int l = blockIdx.x >> 3;
    unsigned sl = blockIdx.x & 7;
    int t = threadIdx.x;
    __shared__ unsigned long long lbuf[CAND_TOT];
    __shared__ unsigned aux[33];

    if (t < NPART) {
        unsigned cc = cnt[l * NPART + t];
        aux[t] = (cc > PART_CAP) ? PART_CAP : cc;
    }
    __syncthreads();
    if (t == 0) {
        unsigned o = 0;
        for (int pp = 0; pp < NPART; pp++) { aux[16 + pp] = o; o += aux[pp]; }
        aux[32] = (o > CAND_TOT) ? CAND_TOT : o;
    }
    __syncthreads();
    unsigned n = aux[32];
    for (int pp = 0; pp < NPART; pp++) {
        unsigned cc = aux[pp], o = aux[16 + pp];
        for (unsigned e = t; e < cc; e += 256) {
            unsigned dst = o + e;
            if (dst < CAND_TOT)
                lbuf[dst] = cand[((size_t)(l * NPART + pp)) * PART_CAP + e];
        }
    }
    __syncthreads();

    unsigned j = sl * 256u + t;
    if (j >= n) return;
    unsigned long long my = lbuf[j];
    unsigned rank = 0;
    #pragma unroll 8
    for (unsigned q = 0; q < n; q++) rank += (lbuf[q] > my) ? 1u : 0u;
    if (rank >= TOPKK) return;

    unsigned idx = ~((unsigned)(my & 0xFFFFFFFFull));
    float4 an = ((const float4*)p.anc[l])[idx];
    float4 dd = ((const float4*)p.reg[l])[(size_t)idx * 2];
    float w = an.z - an.x, h = an.w - an.y;
    float cx = an.x + 0.5f * w, cy = an.y + 0.5f * h;
    float pcx = cx + dd.x * w, pcy = cy + dd.y * h;
    float pw = w * expf(fminf(dd.z, MAXD));
    float ph = h * expf(fminf(dd.w, MAXD));
    float bx = pcx - 0.5f * pw, by = pcy - 0.5f * ph;
    float bz = pcx + 0.5f * pw, bw = pcy + 0.5f * ph;

    const float4* cp = (const float4*)(p.cls[l]) + (size_t)idx * 4;
    float sg[16];
    #pragma unroll
    for (int g = 0; g < 4; g++) {
        float4 v = cp[g];
        sg[4 * g + 0] = 1.0f / (1.0f + expf(-v.x));
        sg[4 * g + 1] = 1.0f / (1.0f + expf(-v.y));
        sg[4 * g + 2] = 1.0f / (1.0f + expf(-v.z));
        sg[4 * g + 3] = 1.0f / (1.0f + expf(-v.w));
    }
    // 16 rows of [bx,by,bz,bw,score,tag] == 24 float4s, 384B contiguous
    float4* q = (float4*)(out + (size_t)(l * TOPKK + rank) * (NCLS * 6));
    #pragma unroll
    for (int g = 0; g < 8; g++) {
        float ta = (float)(2 * g + 1), tb = (float)(2 * g + 2);
        q[3 * g + 0] = make_float4(bx, by, bz, bw);
        q[3 * g + 1] = make_float4(sg[2 * g], ta, bx, by);
        q[3 * g + 2] = make_float4(bz, bw, sg[2 * g + 1], tb);
    }
}

extern "C" void kernel_launch(void* const* d_in, const int* in_sizes, int n_in,
                              void* d_out, int out_size, void* d_ws, size_t ws_size,
                              hipStream_t stream) {
    (void)in_sizes; (void)n_in; (void)out_size; (void)ws_size;
    Ptrs p;
    for (int l = 0; l < NLEV; l++) {
        p.anc[l] = (const float*)d_in[3 * l + 0];
        p.cls[l] = (const float*)d_in[3 * l + 1];
        p.reg[l] = (const float*)d_in[3 * l + 2];
    }
    char* w = (char*)d_ws;
    // layout (bytes):
    //   hist16 : 0        .. 5242880   \  one contiguous memset (5243200 B)
    //   cnt    : 5242880  .. 5243200   /
    //   thresh : 5243200  .. 5243264      (written by k_select before read)
    //   keys   : 5243264  .. 8385920     (written before read, no memset)
    //   cand   : 8385920  .. 8549760     (guarded by cnt, no memset)
    unsigned* hist16 = (unsigned*)w;
    unsigned* cnt    = (unsigned*)(w + 5242880);
    unsigned* thr    = (unsigned*)(w + 5243200);
    unsigned* keys   = (unsigned*)(w + 5243264);
    unsigned long long* cand = (unsigned long long*)(w + 8385920);
    float* out = (float*)d_out;
    int nb = NTOT / 256;                     // 3069, exact

    (void)hipMemsetAsync(w, 0, 5243200, stream);
    k_keys_hist16<<<nb, 256, 0, stream>>>(p, keys, hist16);
    k_select<<<NLEV, 256, 0, stream>>>(hist16, thr);
    k_compact<<<nb, 256, 0, stream>>>(keys, thr, cnt, cand);
    k_rank_emit<<<NLEV * 8, 256, 0, stream>>>(p, cnt, cand, out);
}